// Round 6
// baseline (121.437 us; speedup 1.0000x reference)
//
#include <hip/hip_runtime.h>
#include <hip/hip_bf16.h>
#include <math.h>

// Problem constants
#define BATCH   2048
#define TWO_B   4096
#define DIM     1024
#define NBLK4   256           // 16x16 grid of 256x256 tiles
// 1 / (0.07 * ln(2)) : exp(s/T) = exp2(s * INV_T_LOG2E)
#define INV_T_LOG2E 20.60991907f
#define INV_T       14.285714285714286f
#define INV_127SQ   6.200013640958517e-05f   // 1/(127*127)

typedef float f32x4 __attribute__((ext_vector_type(4)));
typedef int   i32x4 __attribute__((ext_vector_type(4)));

// Scratch in __device__ globals (R14: the 256 MiB d_ws poison fill is
// unconditional, ~43 us/iter serial prelude; only our ~53 us is attackable).
// z is int8 (q = rint(127*z), fixed scale since rows are unit-norm) — R17
// proved i8 MFMA numerics pass (absmax 0.0) and halve the matrix-pipe time.
__device__ __attribute__((aligned(4096))) char g_z[(size_t)TWO_B * DIM]; // i8, 4 MB
__device__ float        g_rowsum[TWO_B];
__device__ float        g_positives[TWO_B];
__device__ unsigned int g_counter;

// ---------------------------------------------------------------------------
// Kernel 1: L2-normalize 4096 rows -> int8 q[4096][1024] (4 MB).
// Wave-per-row; zero-inits rowsum + completion counter. No fences.
// ---------------------------------------------------------------------------
__global__ __launch_bounds__(256) void normalize_kernel(
        const float* __restrict__ feat) {
    const int lane = threadIdx.x & 63;
    const int row  = blockIdx.x * 4 + (threadIdx.x >> 6);
    if (lane == 0) g_rowsum[row] = 0.0f;
    if (blockIdx.x == 0 && threadIdx.x == 0) g_counter = 0u;

    const float* src = feat + (row < BATCH ? (size_t)row * (2 * DIM)
                                           : (size_t)(row - BATCH) * (2 * DIM) + DIM);
    float4 v[4];
    float ss = 0.0f;
    #pragma unroll
    for (int t = 0; t < 4; ++t) {
        v[t] = ((const float4*)src)[t * 64 + lane];
        ss += v[t].x * v[t].x + v[t].y * v[t].y + v[t].z * v[t].z + v[t].w * v[t].w;
    }
    #pragma unroll
    for (int off = 32; off; off >>= 1) ss += __shfl_xor(ss, off, 64);
    const float s127 = 127.0f / fmaxf(sqrtf(ss), 1e-12f);
    int4 o;
    int* op = (int*)&o;
    #pragma unroll
    for (int t = 0; t < 4; ++t) {
        const int b0 = __float2int_rn(v[t].x * s127) & 255;
        const int b1 = __float2int_rn(v[t].y * s127) & 255;
        const int b2 = __float2int_rn(v[t].z * s127) & 255;
        const int b3 = __float2int_rn(v[t].w * s127) & 255;
        op[t] = b0 | (b1 << 8) | (b2 << 16) | (b3 << 24);
    }
    ((int4*)(g_z + (size_t)row * DIM))[lane] = o;   // 64 lanes x 16 B = one row
}

// ---------------------------------------------------------------------------
// Kernel 2 (R19): sim = (q q^T)/127^2 via mfma_i32_16x16x64_i8 — ZERO LDS.
// Diagnosis chain: R13-R18 all plateau at ~40-45 us regardless of dtype,
// phase count, or tile size, because all share the barrier-synchronized
// global_load_lds staging structure; the per-CU staging path + per-K-step
// vmcnt(0) drain is the binding resource (R18: doubling staged bytes/CU
// regressed; occupancy never rose). z is 4 MB and each XCD's panel working
// set (~3 MB) is L2-resident -> staging is pure overhead (learn_hip
// common-mistake #7). R19 streams A/B fragments directly from L2 with
// global_load_dwordx4, explicit 2-deep named register pipeline, NO barriers
// in the K-loop (waves fully independent). Shell otherwise = R17 winner:
// 256x256 tiles, 8 waves, 256 blocks, XCD 4x8 region swizzle (keeps the
// 3 MB working set on one XCD-L2), shfl epilogue, fence-free finalize.
// Canonical (row, k) addressing delivers the same operands the swizzled
// LDS path did (absmax 0.0 proven on identical math).
// ---------------------------------------------------------------------------
__global__ __launch_bounds__(512) void gemm_fused(
        float* __restrict__ out) {
    // XCD-aware swizzle: id&7 = round-robin XCD; 4x8-tile region per XCD
    const int bid = blockIdx.x;
    const int xcd = bid & 7;
    const int t5  = bid >> 3;                   // 0..31 within region
    const int by  = (xcd >> 1) * 4 + (t5 & 3);
    const int bx  = (xcd & 1) * 8 + (t5 >> 2);
    const int rb  = by * 256;
    const int cb  = bx * 256;

    const int tid  = threadIdx.x;
    const int lane = tid & 63;
    const int wv   = tid >> 6;       // wave 0..7
    const int wr   = wv & 3;         // wave row (0..3) -> 64-row subtile
    const int wc   = wv >> 2;        // wave col (0..1) -> 128-col subtile
    const int q    = lane >> 4;      // quad 0..3
    const int mn   = lane & 15;

    i32x4 acc[4][8] = {};            // i32 accumulators (exact)

    // Per-lane row pointers (canonical i8 K=64 operand layout:
    // lane reads rows (..)+mn, k-slot q*16, 16 contiguous bytes).
    const char* Ap[4];
    const char* Bp[8];
    #pragma unroll
    for (int i = 0; i < 4; ++i)
        Ap[i] = g_z + (size_t)(rb + wr * 64 + i * 16 + mn) * DIM + q * 16;
    #pragma unroll
    for (int j = 0; j < 8; ++j)
        Bp[j] = g_z + (size_t)(cb + wc * 128 + j * 16 + mn) * DIM + q * 16;

    i32x4 a0[4], b0[8], a1[4], b1[8];

    #define LOADF(A, B, KOFF)                                   \
        do {                                                    \
            _Pragma("unroll")                                   \
            for (int i = 0; i < 4; ++i)                         \
                A[i] = *(const i32x4*)(Ap[i] + (KOFF));         \
            _Pragma("unroll")                                   \
            for (int j = 0; j < 8; ++j)                         \
                B[j] = *(const i32x4*)(Bp[j] + (KOFF));         \
        } while (0)

    #define MFMAS(A, B)                                         \
        do {                                                    \
            _Pragma("unroll")                                   \
            for (int i = 0; i < 4; ++i)                         \
                _Pragma("unroll")                               \
                for (int j = 0; j < 8; ++j)                     \
                    acc[i][j] = __builtin_amdgcn_mfma_i32_16x16x64_i8( \
                                    A[i], B[j], acc[i][j], 0, 0, 0);   \
        } while (0)

    // 16 K-steps of 64; 2-deep named register pipeline, no barriers.
    LOADF(a0, b0, 0);
    for (int k0 = 0; k0 < DIM; k0 += 128) {
        LOADF(a1, b1, k0 + 64);
        MFMAS(a0, b0);
        if (k0 + 128 < DIM)
            LOADF(a0, b0, k0 + 128);
        MFMAS(a1, b1);
    }
    #undef LOADF
    #undef MFMAS

    // ---- Epilogue (shfl; C/D col = lane&15, row = q*4 + reg) ----
    #pragma unroll
    for (int i = 0; i < 4; ++i) {
        #pragma unroll
        for (int reg = 0; reg < 4; ++reg) {
            const int r  = rb + wr * 64 + i * 16 + q * 4 + reg;
            const int pc = (r + BATCH) & (TWO_B - 1);
            float local = 0.0f;
            #pragma unroll
            for (int j = 0; j < 8; ++j) {
                const int c = cb + wc * 128 + j * 16 + mn;
                const float s = (float)acc[i][j][reg] * INV_127SQ;
                if (c == pc)   // unique writer per r
                    __hip_atomic_store(&g_positives[r], s, __ATOMIC_RELAXED,
                                       __HIP_MEMORY_SCOPE_AGENT);
                local += (c == r) ? 0.0f : exp2f(s * INV_T_LOG2E);
            }
            local += __shfl_xor(local, 1, 64);
            local += __shfl_xor(local, 2, 64);
            local += __shfl_xor(local, 4, 64);
            local += __shfl_xor(local, 8, 64);
            if (mn == 0) atomicAdd(&g_rowsum[r], local);
        }
    }

    // ---- fence-free last-block finalize (R7/R8/R13, proven) ----
    __shared__ int amLast;
    __syncthreads();
    if (tid == 0) {
        unsigned int old = __hip_atomic_fetch_add(&g_counter, 1u, __ATOMIC_RELAXED,
                                                  __HIP_MEMORY_SCOPE_AGENT);
        amLast = (old == NBLK4 - 1);
    }
    __syncthreads();
    if (amLast) {
        float acc2 = 0.0f;
        for (int r = tid; r < TWO_B; r += 512) {
            float rs = __hip_atomic_load(&g_rowsum[r], __ATOMIC_RELAXED,
                                         __HIP_MEMORY_SCOPE_AGENT);
            float p  = __hip_atomic_load(&g_positives[r], __ATOMIC_RELAXED,
                                         __HIP_MEMORY_SCOPE_AGENT);
            acc2 += logf(rs) - p * INV_T;
        }
        #pragma unroll
        for (int off = 32; off; off >>= 1) acc2 += __shfl_down(acc2, off, 64);
        __shared__ float s_part[8];
        if ((tid & 63) == 0) s_part[tid >> 6] = acc2;
        __syncthreads();
        if (tid == 0) {
            float tot = 0.0f;
            #pragma unroll
            for (int w = 0; w < 8; ++w) tot += s_part[w];
            out[0] = tot * (1.0f / TWO_B);
        }
    }
}

extern "C" void kernel_launch(void* const* d_in, const int* in_sizes, int n_in,
                              void* d_out, int out_size, void* d_ws, size_t ws_size,
                              hipStream_t stream) {
    const float* feat = (const float*)d_in[0];
    float* out = (float*)d_out;
    (void)d_ws; (void)ws_size;   // poison fill is unconditional (R14) — ws unused

    normalize_kernel<<<TWO_B / 4, 256, 0, stream>>>(feat);
    gemm_fused<<<NBLK4, 512, 0, stream>>>(out);
}

// Round 7
// 101.680 us; speedup vs baseline: 1.1943x; 1.1943x over previous
//
#include <hip/hip_runtime.h>
#include <hip/hip_bf16.h>
#include <math.h>

// Problem constants
#define BATCH   2048
#define TWO_B   4096
#define DIM     1024
#define NBLK4   256           // 16x16 grid of 256x256 tiles
// 1 / (0.07 * ln(2)) : exp(s/T) = exp2(s * INV_T_LOG2E)
#define INV_T_LOG2E 20.60991907f
#define INV_T       14.285714285714286f
#define INV_127SQ   6.200013640958517e-05f   // 1/(127*127)

typedef float f32x4 __attribute__((ext_vector_type(4)));
typedef int   i32x4 __attribute__((ext_vector_type(4)));

// Scratch in __device__ globals (R14: the 256 MiB d_ws poison fill is
// unconditional; only our ~50 us is attackable).
// R20 diagnosis: R13-R19 — five structurally different GEMM bodies (fp8/i8,
// 2-phase/8-phase, 128^2/256^2, LDS/no-LDS, barriers/no-barriers) ALL land
// at 42-61 us with the same counters (MfmaUtil ~11%, VALUBusy ~12%, HBM ~4%,
// occ ~19%). The one invariant: the epilogue's 131K cross-XCD device-scope
// atomicAdds + last-block finalize that waits for every atomic to retire.
// R20 removes ALL atomics: per-block partials via uncontended plain stores
// (kernel-boundary coherence, same mechanism as the g_z handoff), plus a
// tiny third reduce kernel. GEMM body = R17 best (91.7 us), unchanged.
__device__ __attribute__((aligned(4096))) char g_z[(size_t)TWO_B * DIM]; // i8, 4 MB
__device__ __attribute__((aligned(256))) float g_part[TWO_B][32];        // 512 KB
__device__ float g_positives[TWO_B];

__device__ __forceinline__ void load_lds16(const void* g, void* l) {
    __builtin_amdgcn_global_load_lds(
        (const __attribute__((address_space(1))) void*)g,
        (__attribute__((address_space(3))) void*)l,
        16, 0, 0);
}

// ---------------------------------------------------------------------------
// Kernel 1: L2-normalize 4096 rows -> int8 q[4096][1024] (4 MB).
// Wave-per-row. q = rint(127*z), fixed scale (rows are unit-norm) — R17
// proved i8 numerics pass (absmax 0.0).
// ---------------------------------------------------------------------------
__global__ __launch_bounds__(256) void normalize_kernel(
        const float* __restrict__ feat) {
    const int lane = threadIdx.x & 63;
    const int row  = blockIdx.x * 4 + (threadIdx.x >> 6);

    const float* src = feat + (row < BATCH ? (size_t)row * (2 * DIM)
                                           : (size_t)(row - BATCH) * (2 * DIM) + DIM);
    float4 v[4];
    float ss = 0.0f;
    #pragma unroll
    for (int t = 0; t < 4; ++t) {
        v[t] = ((const float4*)src)[t * 64 + lane];
        ss += v[t].x * v[t].x + v[t].y * v[t].y + v[t].z * v[t].z + v[t].w * v[t].w;
    }
    #pragma unroll
    for (int off = 32; off; off >>= 1) ss += __shfl_xor(ss, off, 64);
    const float s127 = 127.0f / fmaxf(sqrtf(ss), 1e-12f);
    int4 o;
    int* op = (int*)&o;
    #pragma unroll
    for (int t = 0; t < 4; ++t) {
        const int b0 = __float2int_rn(v[t].x * s127) & 255;
        const int b1 = __float2int_rn(v[t].y * s127) & 255;
        const int b2 = __float2int_rn(v[t].z * s127) & 255;
        const int b3 = __float2int_rn(v[t].w * s127) & 255;
        op[t] = b0 | (b1 << 8) | (b2 << 16) | (b3 << 24);
    }
    ((int4*)(g_z + (size_t)row * DIM))[lane] = o;   // 64 lanes x 16 B = one row
}

// ---------------------------------------------------------------------------
// Kernel 2 (R20): sim = (q q^T)/127^2 via mfma_i32_16x16x64_i8. GEMM body
// identical to R17 (the 91.7 us best): 256x256 tiles, 8 waves, BK=64 dbuf
// LDS (64 KB), 256 blocks, XOR swizzles (0 conflicts), XCD 4x8 region
// swizzle. ONLY the epilogue changed: plain stores of per-(row, col-stripe,
// wave-half) exp-sums to g_part (no atomics, no counter, no finalize tail).
// ---------------------------------------------------------------------------
__global__ __launch_bounds__(512) void gemm_fused() {
    __shared__ char smem[65536];     // buf: [sA 16K | sB 16K] x2

    // XCD-aware swizzle: id&7 = round-robin XCD; 4x8-tile region per XCD
    const int bid = blockIdx.x;
    const int xcd = bid & 7;
    const int t5  = bid >> 3;                   // 0..31 within region
    const int by  = (xcd >> 1) * 4 + (t5 & 3);
    const int bx  = (xcd & 1) * 8 + (t5 >> 2);
    const int rb  = by * 256;
    const int cb  = bx * 256;

    const int tid  = threadIdx.x;
    const int lane = tid & 63;
    const int wv   = tid >> 6;       // wave 0..7
    const int wr   = wv & 3;         // wave row (0..3) -> 64-row subtile
    const int wc   = wv >> 2;        // wave col (0..1) -> 128-col subtile
    const int q    = lane >> 4;      // quad 0..3
    const int mn   = lane & 15;

    i32x4 acc[4][8] = {};            // i32 accumulators (exact)

    const int lrow  = lane >> 2;                       // row within 16-row chunk
    const int lsegb = ((lane & 3) ^ ((lane >> 3) & 3)) * 16;   // fetch-side XOR swizzle
    const int rslot = (q ^ ((mn >> 1) & 3)) * 16;      // byte offset in 64-B row

    // staging: 32 chunks of 16 rows x 64 B (A: ci 0..15, B: ci 16..31);
    // wave wv stages ci = 4wv..4wv+3.
    size_t goff[4];
    int    loff[4];
    #pragma unroll
    for (int t = 0; t < 4; ++t) {
        const int ci = wv * 4 + t;
        const bool isB = ci >= 16;
        const int  cc  = ci & 15;
        goff[t] = (size_t)((isB ? cb : rb) + cc * 16 + lrow) * DIM + lsegb;
        loff[t] = (isB ? 16384 : 0) + cc * 1024;
    }

    // preload K-tile 0 into buffer 0
    #pragma unroll
    for (int t = 0; t < 4; ++t)
        load_lds16(g_z + goff[t], smem + loff[t]);
    __syncthreads();

    int cur = 0;
    for (int k0 = 64; k0 <= DIM; k0 += 64) {
        if (k0 < DIM) {   // prefetch next K-tile into the other buffer
            const int nxt = cur ^ 1;
            #pragma unroll
            for (int t = 0; t < 4; ++t)
                load_lds16(g_z + goff[t] + k0, smem + nxt * 32768 + loff[t]);
        }
        const char* cA = smem + cur * 32768;
        const char* cB = cA + 16384;

        i32x4 af[4], bf[8];
        #pragma unroll
        for (int i = 0; i < 4; ++i)
            af[i] = *(const i32x4*)&cA[(wr * 64 + i * 16 + mn) * 64 + rslot];
        #pragma unroll
        for (int j = 0; j < 8; ++j)
            bf[j] = *(const i32x4*)&cB[(wc * 128 + j * 16 + mn) * 64 + rslot];
        #pragma unroll
        for (int i = 0; i < 4; ++i)
            #pragma unroll
            for (int j = 0; j < 8; ++j)
                acc[i][j] = __builtin_amdgcn_mfma_i32_16x16x64_i8(
                                af[i], bf[j], acc[i][j], 0, 0, 0);
        __syncthreads();
        cur ^= 1;
    }

    // ---- Epilogue: exp-sum partials, plain uncontended stores ----
    // C/D col = lane&15, row = q*4 + reg. After the 4-step shfl reduce,
    // lanes with mn==0 hold the sum over this wave's 128-col half.
    const int slot = bx * 2 + wc;    // 0..31, unique per (col-tile, half)
    #pragma unroll
    for (int i = 0; i < 4; ++i) {
        #pragma unroll
        for (int reg = 0; reg < 4; ++reg) {
            const int r  = rb + wr * 64 + i * 16 + q * 4 + reg;
            const int pc = (r + BATCH) & (TWO_B - 1);
            float local = 0.0f;
            #pragma unroll
            for (int j = 0; j < 8; ++j) {
                const int c = cb + wc * 128 + j * 16 + mn;
                const float s = (float)acc[i][j][reg] * INV_127SQ;
                if (c == pc)   // unique writer per r across the whole grid
                    g_positives[r] = s;
                local += (c == r) ? 0.0f : exp2f(s * INV_T_LOG2E);
            }
            local += __shfl_xor(local, 1, 64);
            local += __shfl_xor(local, 2, 64);
            local += __shfl_xor(local, 4, 64);
            local += __shfl_xor(local, 8, 64);
            if (mn == 0) g_part[r][slot] = local;   // unique (r, slot)
        }
    }
}

// ---------------------------------------------------------------------------
// Kernel 3 (R20): reduce — rowsum = sum of 32 partials, loss = mean over
// rows of log(rowsum) - positives/T. Single block, 16 waves; 512 KB of
// just-written (kernel-boundary-coherent) data. Writes out[0] exactly once.
// ---------------------------------------------------------------------------
__global__ __launch_bounds__(1024) void reduce_kernel(float* __restrict__ out) {
    const int tid = threadIdx.x;
    float acc = 0.0f;
    for (int r = tid; r < TWO_B; r += 1024) {
        const float4* pr = (const float4*)g_part[r];
        float s = 0.0f;
        #pragma unroll
        for (int u = 0; u < 8; ++u) {
            const float4 v = pr[u];
            s += v.x + v.y + v.z + v.w;
        }
        acc += logf(s) - g_positives[r] * INV_T;
    }
    #pragma unroll
    for (int off = 32; off; off >>= 1) acc += __shfl_down(acc, off, 64);
    __shared__ float sp[16];
    if ((tid & 63) == 0) sp[tid >> 6] = acc;
    __syncthreads();
    if (tid == 0) {
        float tot = 0.0f;
        #pragma unroll
        for (int w = 0; w < 16; ++w) tot += sp[w];
        out[0] = tot * (1.0f / TWO_B);
    }
}

extern "C" void kernel_launch(void* const* d_in, const int* in_sizes, int n_in,
                              void* d_out, int out_size, void* d_ws, size_t ws_size,
                              hipStream_t stream) {
    const float* feat = (const float*)d_in[0];
    float* out = (float*)d_out;
    (void)d_ws; (void)ws_size;   // poison fill is unconditional (R14) — ws unused

    normalize_kernel<<<TWO_B / 4, 256, 0, stream>>>(feat);
    gemm_fused<<<NBLK4, 512, 0, stream>>>();
    reduce_kernel<<<1, 1024, 0, stream>>>(out);
}